// Round 5
// baseline (792.819 us; speedup 1.0000x reference)
//
#include <hip/hip_runtime.h>

#define EMBD 384
#define FFN_DIM 1536
#define T_SEQ 200
#define NHEAD 6
#define BATCH 256

typedef __bf16 bf16x8_t __attribute__((ext_vector_type(8)));
typedef short s16x8_t __attribute__((ext_vector_type(8)));
typedef float f32x4_t __attribute__((ext_vector_type(4)));

__device__ __forceinline__ float bf2f(unsigned short h) {
  return __builtin_bit_cast(float, (unsigned)h << 16);
}
__device__ __forceinline__ unsigned short f2bf(float f) {
  unsigned u = __builtin_bit_cast(unsigned, f);
  u += 0x7fffu + ((u >> 16) & 1u);  // RTNE
  return (unsigned short)(u >> 16);
}
__device__ __forceinline__ void async_cp16(const void* g, void* l) {
  __builtin_amdgcn_global_load_lds(
      (const __attribute__((address_space(1))) unsigned int*)g,
      (__attribute__((address_space(3))) unsigned int*)l, 16, 0, 0);
}

// ---------------- static workspace layout (~3.6 MB) ----------------
static constexpr size_t OFF_WQKV  = 0;
static constexpr size_t OFF_WPROJ = OFF_WQKV  + (size_t)1152 * 384 * 2;
static constexpr size_t OFF_W1    = OFF_WPROJ + (size_t)384 * 384 * 2;
static constexpr size_t OFF_W2    = OFF_W1    + (size_t)1536 * 384 * 2;
static constexpr size_t OFF_BIAS  = OFF_W2    + (size_t)384 * 1536 * 2;
static constexpr size_t OFF_FLAG  = OFF_BIAS  + 4096 * 4;
static constexpr size_t OFF_DYN   = OFF_FLAG + 256;

// ---------------- dtype detect ----------------
__global__ void detect_dtype(const unsigned short* __restrict__ xr, int* __restrict__ flag) {
  int tid = threadIdx.x;
  int cnt = 0;
  for (int i = tid; i < 4096; i += 256) {
    float a = fabsf(bf2f(xr[2 * i]));
    cnt += (a > 1e-5f && a < 32.f) ? 1 : 0;
  }
#pragma unroll
  for (int off = 32; off; off >>= 1) cnt += __shfl_xor(cnt, off);
  __shared__ int tot;
  if (tid == 0) tot = 0;
  __syncthreads();
  if ((tid & 63) == 0) atomicAdd(&tot, cnt);
  __syncthreads();
  if (tid == 0) *flag = (tot > 2048) ? 1 : 0;
}

// ---------------- fused bias/gain convert ----------------
__global__ void cvt_all(const void* bproj, const void* b1, const void* b2,
                        const void* g1, const void* be1, const void* g2, const void* be2,
                        float* __restrict__ dst, const int* __restrict__ flagp) {
  int i = blockIdx.x * 256 + threadIdx.x;
  if (i >= 3840) return;
  const void* src; int loc;
  if (i < 384)       { src = bproj; loc = i; }
  else if (i < 1920) { src = b1;    loc = i - 384; }
  else if (i < 2304) { src = b2;    loc = i - 1920; }
  else if (i < 2688) { src = g1;    loc = i - 2304; }
  else if (i < 3072) { src = be1;   loc = i - 2688; }
  else if (i < 3456) { src = g2;    loc = i - 3072; }
  else               { src = be2;   loc = i - 3456; }
  dst[i] = (*flagp) ? bf2f(((const unsigned short*)src)[loc]) : ((const float*)src)[loc];
}

// ------------- coalesced weight pack: LDS-tiled 64x64 transpose -------------
// W[K][N] row-major -> Wt[N][K].  432 tile-blocks.
__global__ __launch_bounds__(256) void pack_tr(const void* Wq, const void* Wk,
                                               const void* Wv, const void* Wp,
                                               const void* W1, const void* W2,
                                               char* __restrict__ ws,
                                               const int* __restrict__ flagp) {
  __shared__ unsigned short T[64 * 80];  // +16 pad, 160B rows (16B aligned)
  int t = blockIdx.x;
  const void* W; unsigned short* Wt; int N, ldt, k0, n0;
  if (t < 144) {
    int which = t / 36, r = t % 36;
    k0 = (r / 6) * 64; n0 = (r % 6) * 64; N = 384;
    if (which < 3) { W = (which == 0 ? Wq : which == 1 ? Wk : Wv);
                     Wt = (unsigned short*)(ws + OFF_WQKV) + which * 147456; ldt = 384; }
    else           { W = Wp; Wt = (unsigned short*)(ws + OFF_WPROJ); ldt = 384; }
  } else if (t < 288) {
    int r = t - 144; k0 = (r / 24) * 64; n0 = (r % 24) * 64; N = 1536;
    W = W1; Wt = (unsigned short*)(ws + OFF_W1); ldt = 384;
  } else {
    int r = t - 288; k0 = (r / 6) * 64; n0 = (r % 6) * 64; N = 384;
    W = W2; Wt = (unsigned short*)(ws + OFF_W2); ldt = 1536;
  }
  const int tid = threadIdx.x;
  const int rr = tid >> 2, cc = (tid & 3) * 16;
  if (*flagp) {
    const unsigned short* Ws = (const unsigned short*)W;
    *(s16x8_t*)&T[rr * 80 + cc] = *(const s16x8_t*)&Ws[(size_t)(k0 + rr) * N + n0 + cc];
    *(s16x8_t*)&T[rr * 80 + cc + 8] = *(const s16x8_t*)&Ws[(size_t)(k0 + rr) * N + n0 + cc + 8];
    __syncthreads();
    // write transposed: thread handles out-row n=rr, k-chunk cc..cc+15
    s16x8_t o0, o1;
#pragma unroll
    for (int j = 0; j < 8; ++j) o0[j] = (short)T[(cc + j) * 80 + rr];
#pragma unroll
    for (int j = 0; j < 8; ++j) o1[j] = (short)T[(cc + 8 + j) * 80 + rr];
    *(s16x8_t*)&Wt[(size_t)(n0 + rr) * ldt + k0 + cc] = o0;
    *(s16x8_t*)&Wt[(size_t)(n0 + rr) * ldt + k0 + cc + 8] = o1;
  } else {
    const float* Wf = (const float*)W;
#pragma unroll
    for (int j = 0; j < 16; ++j)
      Wt[(size_t)(n0 + cc + j) * ldt + k0 + rr] = f2bf(Wf[(size_t)(k0 + rr) * N + n0 + cc + j]);
  }
}

// ---------------- LayerNorm: one wave per row, vectorized bf16x8 ----------------
__global__ __launch_bounds__(256) void ln_kernel(const void* __restrict__ xin, int row0,
                                                 const float* __restrict__ g,
                                                 const float* __restrict__ be,
                                                 unsigned short* __restrict__ out,
                                                 int isbf_mode, const int* __restrict__ flagp) {
  int rloc = blockIdx.x * 4 + (threadIdx.x >> 6);
  int lane = threadIdx.x & 63;
  int isbf = (isbf_mode >= 0) ? isbf_mode : *flagp;
  size_t row = (size_t)(row0 + rloc);
  float v[8];
  float sum = 0.f;
  const int act = lane < 48;
  const int c0 = lane * 8;
  if (act) {
    if (isbf) {
      s16x8_t xv = *(const s16x8_t*)((const unsigned short*)xin + row * EMBD + c0);
#pragma unroll
      for (int i = 0; i < 8; ++i) { v[i] = bf2f((unsigned short)xv[i]); sum += v[i]; }
    } else {
      const float* xr = (const float*)xin + row * EMBD + c0;
#pragma unroll
      for (int i = 0; i < 8; ++i) { v[i] = xr[i]; sum += v[i]; }
    }
  } else {
#pragma unroll
    for (int i = 0; i < 8; ++i) v[i] = 0.f;
  }
#pragma unroll
  for (int off = 32; off; off >>= 1) sum += __shfl_xor(sum, off);
  float mean = sum * (1.f / EMBD);
  float var = 0.f;
  if (act) {
#pragma unroll
    for (int i = 0; i < 8; ++i) { float d = v[i] - mean; var += d * d; }
  }
#pragma unroll
  for (int off = 32; off; off >>= 1) var += __shfl_xor(var, off);
  float rstd = rsqrtf(var * (1.f / EMBD) + 1e-5f);
  if (act) {
    s16x8_t ov;
#pragma unroll
    for (int i = 0; i < 8; ++i)
      ov[i] = (short)f2bf((v[i] - mean) * rstd * g[c0 + i] + be[c0 + i]);
    *(s16x8_t*)(out + (size_t)rloc * EMBD + c0) = ov;
  }
}

// ------------- bf16 MFMA GEMM: 128x128 block, 64x64 wave tile, BK=64 -------------
template <int MODE>
__global__ __launch_bounds__(256, 3) void gemm_kernel(
    const unsigned short* __restrict__ A, int lda,
    const unsigned short* __restrict__ Bt, int K,
    const float* __restrict__ bias,
    const void* __restrict__ R, int ldr, int rrow0,
    void* __restrict__ Cv, int ldc, int crow0,
    int Mrows, int NX, int NY, const int* __restrict__ flagp) {
  __shared__ unsigned short As[128 * 64];
  __shared__ unsigned short Bs[128 * 64];
  const int g = blockIdx.x;
  const int xcd = g & 7, s = g >> 3;
  const int j = s / NX, xn = s - j * NX;
  const int y = xcd + 8 * j;
  if (y >= NY) return;
  const int n0 = xn * 128;
  const int m0 = y * 128;
  const int tid = threadIdx.x;
  const int wv = tid >> 6, lane = tid & 63;
  const int wr = wv >> 1, wc = wv & 1;
  const int l = lane & 15, quad = lane >> 4;
  f32x4_t acc[4][4];
#pragma unroll
  for (int i = 0; i < 4; ++i)
#pragma unroll
    for (int jj = 0; jj < 4; ++jj) acc[i][jj] = (f32x4_t){0.f, 0.f, 0.f, 0.f};

  for (int kc = 0; kc < K; kc += 64) {
#pragma unroll
    for (int i = 0; i < 4; ++i) {
      int c = (wv * 4 + i) * 64 + lane;
      int row = c >> 3;
      int kk = ((c & 7) ^ (row & 7)) * 8;
      int ar = m0 + row;
      if (ar >= Mrows) ar = Mrows - 1;
      async_cp16(A + (size_t)ar * lda + kc + kk, As + (wv * 4 + i) * 512);
    }
#pragma unroll
    for (int i = 0; i < 4; ++i) {
      int c = (wv * 4 + i) * 64 + lane;
      int row = c >> 3;
      int kk = ((c & 7) ^ (row & 7)) * 8;
      async_cp16(Bt + (size_t)(n0 + row) * K + kc + kk, Bs + (wv * 4 + i) * 512);
    }
    __syncthreads();
#pragma unroll
    for (int ks = 0; ks < 2; ++ks) {
      bf16x8_t af[4], bfr[4];
#pragma unroll
      for (int gg = 0; gg < 4; ++gg) {
        int row = wr * 64 + gg * 16 + l;
        int ch = row * 8 + ((quad + ks * 4) ^ (row & 7));
        af[gg] = *(const bf16x8_t*)&As[ch * 8];
        int nrw = wc * 64 + gg * 16 + l;
        int nch = nrw * 8 + ((quad + ks * 4) ^ (nrw & 7));
        bfr[gg] = *(const bf16x8_t*)&Bs[nch * 8];
      }
#pragma unroll
      for (int i = 0; i < 4; ++i)
#pragma unroll
        for (int jj = 0; jj < 4; ++jj)
          acc[i][jj] = __builtin_amdgcn_mfma_f32_16x16x32_bf16(af[i], bfr[jj], acc[i][jj], 0, 0, 0);
    }
    __syncthreads();
  }

  int isbf = flagp ? *flagp : 1;
#pragma unroll
  for (int i = 0; i < 4; ++i) {
#pragma unroll
    for (int jj = 0; jj < 4; ++jj) {
#pragma unroll
      for (int r = 0; r < 4; ++r) {
        int row = m0 + wr * 64 + i * 16 + quad * 4 + r;
        int col = n0 + wc * 64 + jj * 16 + l;
        if (row >= Mrows) continue;
        float v = acc[i][jj][r];
        if (MODE == 0) {
          ((unsigned short*)Cv)[(size_t)row * ldc + col] = f2bf(v);
        } else if (MODE == 1) {
          v += bias[col];
          ((unsigned short*)Cv)[(size_t)row * ldc + col] = f2bf(fmaxf(v, 0.f));
        } else if (MODE == 2) {
          size_t ridx = (size_t)(rrow0 + row) * ldr + col;
          float rv = isbf ? bf2f(((const unsigned short*)R)[ridx]) : ((const float*)R)[ridx];
          ((unsigned short*)Cv)[(size_t)row * ldc + col] = f2bf(v + bias[col] + rv);
        } else {
          float rv = bf2f(((const unsigned short*)R)[(size_t)row * ldr + col]);
          float o = v + bias[col] + rv;
          size_t cidx = (size_t)(crow0 + row) * ldc + col;
          if (isbf)
            ((unsigned short*)Cv)[cidx] = f2bf(o);
          else
            ((float*)Cv)[cidx] = o;
        }
      }
    }
  }
}

// ------------- WIDE GEMM experiment: 128x256 block, 64x128 wave tile -------------
// 2x MFMA per staged A-byte; per-ks 12 ds_read_b128 vs 32 MFMA (MFMA-bound).
// Used for ffn1 (N=1536=6x256). Fused bias+relu, bf16 out.
__global__ __launch_bounds__(256, 2) void gemm_wide(
    const unsigned short* __restrict__ A, int lda,
    const unsigned short* __restrict__ Bt, int K,
    const float* __restrict__ bias,
    void* __restrict__ Cv, int ldc,
    int Mrows, int NX, int NY) {
  __shared__ unsigned short As[128 * 64];   // 16 KB
  __shared__ unsigned short Bs[256 * 64];   // 32 KB
  const int g = blockIdx.x;
  const int xcd = g & 7, s = g >> 3;
  const int j = s / NX, xn = s - j * NX;
  const int y = xcd + 8 * j;
  if (y >= NY) return;
  const int n0 = xn * 256;
  const int m0 = y * 128;
  const int tid = threadIdx.x;
  const int wv = tid >> 6, lane = tid & 63;
  const int wr = wv >> 1, wc = wv & 1;
  const int l = lane & 15, quad = lane >> 4;
  f32x4_t acc[4][8];
#pragma unroll
  for (int i = 0; i < 4; ++i)
#pragma unroll
    for (int jj = 0; jj < 8; ++jj) acc[i][jj] = (f32x4_t){0.f, 0.f, 0.f, 0.f};

  for (int kc = 0; kc < K; kc += 64) {
#pragma unroll
    for (int i = 0; i < 4; ++i) {  // A: 1024 chunks
      int c = (wv * 4 + i) * 64 + lane;
      int row = c >> 3;
      int kk = ((c & 7) ^ (row & 7)) * 8;
      int ar = m0 + row;
      if (ar >= Mrows) ar = Mrows - 1;
      async_cp16(A + (size_t)ar * lda + kc + kk, As + (wv * 4 + i) * 512);
    }
#pragma unroll
    for (int i = 0; i < 8; ++i) {  // B: 2048 chunks
      int c = (wv * 8 + i) * 64 + lane;
      int row = c >> 3;
      int kk = ((c & 7) ^ (row & 7)) * 8;
      async_cp16(Bt + (size_t)(n0 + row) * K + kc + kk, Bs + (wv * 8 + i) * 512);
    }
    __syncthreads();
#pragma unroll
    for (int ks = 0; ks < 2; ++ks) {
      bf16x8_t af[4], bfr[8];
#pragma unroll
      for (int gg = 0; gg < 4; ++gg) {
        int row = wr * 64 + gg * 16 + l;
        int ch = row * 8 + ((quad + ks * 4) ^ (row & 7));
        af[gg] = *(const bf16x8_t*)&As[ch * 8];
      }
#pragma unroll
      for (int jj = 0; jj < 8; ++jj) {
        int nrw = wc * 128 + jj * 16 + l;
        int nch = nrw * 8 + ((quad + ks * 4) ^ (nrw & 7));
        bfr[jj] = *(const bf16x8_t*)&Bs[nch * 8];
      }
#pragma unroll
      for (int i = 0; i < 4; ++i)
#pragma unroll
        for (int jj = 0; jj < 8; ++jj)
          acc[i][jj] = __builtin_amdgcn_mfma_f32_16x16x32_bf16(af[i], bfr[jj], acc[i][jj], 0, 0, 0);
    }
    __syncthreads();
  }

#pragma unroll
  for (int i = 0; i < 4; ++i) {
#pragma unroll
    for (int jj = 0; jj < 8; ++jj) {
#pragma unroll
      for (int r = 0; r < 4; ++r) {
        int row = m0 + wr * 64 + i * 16 + quad * 4 + r;
        int col = n0 + wc * 128 + jj * 16 + l;
        if (row >= Mrows) continue;
        float v = acc[i][jj][r] + bias[col];
        ((unsigned short*)Cv)[(size_t)row * ldc + col] = f2bf(fmaxf(v, 0.f));
      }
    }
  }
}

// ---------------- MFMA attention: one block per (b_local, h) ----------------
// LDS 52 KB -> 3 blocks/CU. Stride 208: PV k-loop capped at col 191; the
// s in [192,200) remainder is VALU for the single wave that needs it.
__global__ __launch_bounds__(256, 3) void attn_kernel(const unsigned short* __restrict__ qkv,
                                                      unsigned short* __restrict__ att) {
  __shared__ unsigned short Vt[64 * 208];  // [d][s]
  __shared__ unsigned short Ps[64 * 208];  // P rows (wave-private 16-row bands)
  const int bh = blockIdx.x;
  const int b = bh / NHEAD, h = bh % NHEAD;
  const size_t base = (size_t)b * T_SEQ * 1152;
  const int tid = threadIdx.x;
  const int w = tid >> 6, lane = tid & 63;
  const int l = lane & 15, quad = lane >> 4;

  for (int idx = tid; idx < 1600; idx += 256) {
    int s = idx >> 3, d0 = (idx & 7) * 8;
    s16x8_t vv = *(const s16x8_t*)(qkv + base + (size_t)s * 1152 + 768 + h * 64 + d0);
#pragma unroll
    for (int i = 0; i < 8; ++i) Vt[(d0 + i) * 208 + s] = (unsigned short)vv[i];
  }
  for (int idx = tid; idx < 64 * 8; idx += 256) {
    int d = idx >> 3, c = idx & 7;
    Vt[d * 208 + 200 + c] = 0;
  }
  {
    s16x8_t zz = {0, 0, 0, 0, 0, 0, 0, 0};
    for (int idx = tid; idx < 1664; idx += 256) *(s16x8_t*)&Ps[idx * 8] = zz;
  }
  __syncthreads();

  const float scale = 0.051031036307982884f;  // 384^-0.5 (embd, not head_size!)
  const unsigned short* kp = qkv + base + 384 + h * 64;
  for (int t0 = 0; t0 < T_SEQ; t0 += 64) {
    if (t0 + w * 16 >= T_SEQ) continue;  // wave-uniform, no barriers inside
    int tq = t0 + w * 16 + l;
    const unsigned short* qp = qkv + base + (size_t)tq * 1152 + h * 64;
    bf16x8_t qa0 = *(const bf16x8_t*)(qp + quad * 8);
    bf16x8_t qa1 = *(const bf16x8_t*)(qp + 32 + quad * 8);
    const int cmax = (t0 >> 4) + w + 1;
    f32x4_t sa[13];
#pragma unroll
    for (int c = 0; c < 13; ++c) {
      if (c < cmax) {
        const unsigned short* kr = kp + (size_t)(c * 16 + l) * 1152;
        bf16x8_t kb0 = *(const bf16x8_t*)(kr + quad * 8);
        bf16x8_t kb1 = *(const bf16x8_t*)(kr + 32 + quad * 8);
        f32x4_t z = (f32x4_t){0.f, 0.f, 0.f, 0.f};
        z = __builtin_amdgcn_mfma_f32_16x16x32_bf16(qa0, kb0, z, 0, 0, 0);
        sa[c] = __builtin_amdgcn_mfma_f32_16x16x32_bf16(qa1, kb1, z, 0, 0, 0);
      }
    }
#pragma unroll
    for (int r = 0; r < 4; ++r) {
      int t = t0 + w * 16 + quad * 4 + r;
      float tv[13];
      float mx = -1e30f;
#pragma unroll
      for (int c = 0; c < 13; ++c) {
        if (c < cmax) {
          int col = c * 16 + l;
          float v = sa[c][r] * scale;
          tv[c] = (col <= t) ? v : -1e30f;
          mx = fmaxf(mx, tv[c]);
        }
      }
#pragma unroll
      for (int off = 1; off < 16; off <<= 1) mx = fmaxf(mx, __shfl_xor(mx, off));
      float sum = 0.f;
#pragma unroll
      for (int c = 0; c < 13; ++c) {
        if (c < cmax) {
          float p = __expf(tv[c] - mx);
          tv[c] = p;
          sum += p;
        }
      }
#pragma unroll
      for (int off = 1; off < 16; off <<= 1) sum += __shfl_xor(sum, off);
      float inv = 1.f / sum;
#pragma unroll
      for (int c = 0; c < 13; ++c) {
        if (c < cmax)
          Ps[(w * 16 + quad * 4 + r) * 208 + c * 16 + l] = f2bf(tv[c] * inv);
      }
    }
    // O = P @ V : full 32-wide k-steps up to col 191 (P zero-padded => ceil safe)
    int send = t0 + w * 16 + 16;
    int smax = (send > 192) ? 192 : send;
    const int ksteps = (smax + 31) >> 5;  // <=6 -> max col read 191
    f32x4_t oa[4];
#pragma unroll
    for (int d = 0; d < 4; ++d) oa[d] = (f32x4_t){0.f, 0.f, 0.f, 0.f};
    for (int ks = 0; ks < ksteps; ++ks) {
      bf16x8_t pa = *(const bf16x8_t*)&Ps[(w * 16 + l) * 208 + ks * 32 + quad * 8];
#pragma unroll
      for (int d = 0; d < 4; ++d) {
        bf16x8_t vb = *(const bf16x8_t*)&Vt[(d * 16 + l) * 208 + ks * 32 + quad * 8];
        oa[d] = __builtin_amdgcn_mfma_f32_16x16x32_bf16(pa, vb, oa[d], 0, 0, 0);
      }
    }
    if (send > T_SEQ) {  // only (t0=192, w=0): VALU tail for s in [192,200)
#pragma unroll
      for (int r = 0; r < 4; ++r) {
        int trow = w * 16 + quad * 4 + r;
        float p[8];
#pragma unroll
        for (int ss = 0; ss < 8; ++ss) p[ss] = bf2f(Ps[trow * 208 + 192 + ss]);
#pragma unroll
        for (int d = 0; d < 4; ++d) {
          float a = 0.f;
#pragma unroll
          for (int ss = 0; ss < 8; ++ss) a += p[ss] * bf2f(Vt[(d * 16 + l) * 208 + 192 + ss]);
          oa[d][r] += a;
        }
      }
    }
#pragma unroll
    for (int d = 0; d < 4; ++d) {
#pragma unroll
      for (int r = 0; r < 4; ++r) {
        int t = t0 + w * 16 + quad * 4 + r;
        if (t < T_SEQ)
          att[((size_t)b * T_SEQ + t) * EMBD + h * 64 + d * 16 + l] = f2bf(oa[d][r]);
      }
    }
  }
}

extern "C" void kernel_launch(void* const* d_in, const int* in_sizes, int n_in,
                              void* d_out, int out_size, void* d_ws, size_t ws_size,
                              hipStream_t stream) {
  const void* x     = d_in[0];
  const void* Wq    = d_in[1];
  const void* Wk    = d_in[2];
  const void* Wv    = d_in[3];
  const void* Wproj = d_in[4];
  const void* bproj = d_in[5];
  const void* W1    = d_in[6];
  const void* b1    = d_in[7];
  const void* W2    = d_in[8];
  const void* b2    = d_in[9];
  const void* g1    = d_in[10];
  const void* be1   = d_in[11];
  const void* g2    = d_in[12];
  const void* be2   = d_in[13];

  char* ws = (char*)d_ws;
  unsigned short* wqkv_t  = (unsigned short*)(ws + OFF_WQKV);
  unsigned short* wproj_t = (unsigned short*)(ws + OFF_WPROJ);
  unsigned short* w1_t    = (unsigned short*)(ws + OFF_W1);
  unsigned short* w2_t    = (unsigned short*)(ws + OFF_W2);
  float*          bias_f  = (float*)(ws + OFF_BIAS);
  int*            flag    = (int*)(ws + OFF_FLAG);

  int Bc = BATCH;
  while (Bc > 1 && OFF_DYN + (size_t)Bc * T_SEQ * 6144 > ws_size) Bc >>= 1;
  if (OFF_DYN + (size_t)Bc * T_SEQ * 6144 > ws_size) return;
  const int NC = BATCH / Bc;
  const int Mc = Bc * T_SEQ;
  const int NY = (Mc + 127) / 128;
  const int NYpad = (NY + 7) & ~7;

  char* bufA = ws + OFF_DYN;                  // qkv; then x2(bf16)+h2
  char* bufB = bufA + (size_t)Mc * 2304;      // h; then att
  char* bufC = bufB + (size_t)Mc * 768;       // mid
  unsigned short* qkv = (unsigned short*)bufA;
  unsigned short* x2  = (unsigned short*)bufA;
  unsigned short* h2  = (unsigned short*)(bufA + (size_t)Mc * 768);
  unsigned short* hb  = (unsigned short*)bufB;
  unsigned short* mid = (unsigned short*)bufC;

  detect_dtype<<<1, 256, 0, stream>>>((const unsigned short*)x, flag);
  cvt_all<<<15, 256, 0, stream>>>(bproj, b1, b2, g1, be1, g2, be2, bias_f, flag);
  pack_tr<<<432, 256, 0, stream>>>(Wq, Wk, Wv, Wproj, W1, W2, ws, flag);

  for (int c = 0; c < NC; ++c) {
    const int row0 = c * Bc * T_SEQ;
    ln_kernel<<<Mc / 4, 256, 0, stream>>>(x, row0, bias_f + 2304, bias_f + 2688, hb, -1, flag);
    gemm_kernel<0><<<9 * NYpad, 256, 0, stream>>>(
        hb, 384, wqkv_t, 384, nullptr, nullptr, 0, 0, qkv, 1152, 0, Mc, 9, NY, nullptr);
    attn_kernel<<<Bc * NHEAD, 256, 0, stream>>>(qkv, hb);
    gemm_kernel<2><<<3 * NYpad, 256, 0, stream>>>(
        hb, 384, wproj_t, 384, bias_f + 0, x, 384, row0, x2, 384, 0, Mc, 3, NY, flag);
    ln_kernel<<<Mc / 4, 256, 0, stream>>>(x2, 0, bias_f + 3072, bias_f + 3456, h2, 1, nullptr);
    // ffn1: WIDE experiment (128x256 tiles, N=1536 -> NX=6)
    gemm_wide<<<6 * NYpad, 256, 0, stream>>>(
        h2, 384, w1_t, 384, bias_f + 384, mid, 1536, Mc, 6, NY);
    gemm_kernel<3><<<3 * NYpad, 256, 0, stream>>>(
        mid, 1536, w2_t, 1536, bias_f + 1920, x2, 384, 0, d_out, 384, row0, Mc, 3, NY, flag);
  }
}